// Round 7
// baseline (295.651 us; speedup 1.0000x reference)
//
#include <hip/hip_runtime.h>

// J-loss via MFMA: T[b,i,k] = sum_p pred[b,i,p] * onehot(target[b,p]==k)
// j[b] = -sum_{i!=k} log(0.5 + 0.5*(T[b,i,i]/n[b,i] - T[b,i,k]/n[b,k]))
//
// R6 post-mortem: staged & direct variants both ~70us @ ~2.2TB/s; TA-scatter,
// atomics, VALU all ruled out. Remaining theory: latency under-hiding at
// <=16 waves/CU. R7: R3 barrier-free direct loads, slimmed for 6 waves/SIMD
// (launch_bounds(256,6), no fused counts, unroll 1), 2304 blocks (512 px)
// so >=6 blocks/CU are actually resident. Counts via ballot kernel.

#define BB 8
#define CC 32
#define HW 147456                 // 384*384
#define CHUNK_PX 512              // pixels per block (4 waves x 128 px)
#define NCHUNK (HW / CHUNK_PX)    // 288
#define CNT_PX 4096               // pixels per count block
#define NCNT (HW / CNT_PX)        // 36

typedef __attribute__((ext_vector_type(8))) short short8;
typedef __attribute__((ext_vector_type(4))) float float4v;
typedef __attribute__((ext_vector_type(4))) unsigned uint4v;

// pack trunc-bf16(lo), trunc-bf16(hi) into one dword: 1 v_perm_b32
__device__ __forceinline__ unsigned pk(float lo, float hi) {
    return __builtin_amdgcn_perm(__float_as_uint(hi), __float_as_uint(lo), 0x07060302u);
}
// packed pair of one-hot bf16 values for classes (ta,tb) vs m
__device__ __forceinline__ unsigned oh2(int ta, int tb, int m) {
    return (ta == m ? 0x3F80u : 0u) | (tb == m ? 0x3F800000u : 0u);
}

__global__ __launch_bounds__(256, 6) void jloss_mfma(
    const float* __restrict__ pred,    // [B][C][HW]
    const int*   __restrict__ target,  // [B][HW]
    float*       __restrict__ T)       // [B][C][C] pre-zeroed
{
    const int tid  = threadIdx.x;
    const int w    = tid >> 6;         // wave 0..3
    const int l    = tid & 63;
    const int quad = l >> 4;
    const int m    = l & 15;
    const int blk  = blockIdx.x;
    const int b    = blk / NCHUNK;
    const int chunk= blk % NCHUNK;

    const long pb_wave = (long)chunk * CHUNK_PX + w * 128;  // wave owns 128 px
    const float* predb = pred + (long)b * CC * HW;
    const int*   tgtb  = target + (long)b * HW;

    float4v acc00 = {0,0,0,0}, acc01 = {0,0,0,0};
    float4v acc10 = {0,0,0,0}, acc11 = {0,0,0,0};

    const float* p0 = predb + (long)m * HW + pb_wave + quad * 8;  // channel m
    const float* p1 = p0 + (long)16 * HW;                         // channel m+16
    const int*   tp = tgtb + pb_wave + quad * 8;

    #pragma unroll 1
    for (int ks = 0; ks < 4; ++ks) {   // 4 K-steps of 32 pixels
        const int o = ks * 32;
        const float4 a0l = *(const float4*)(p0 + o);
        const float4 a0h = *(const float4*)(p0 + o + 4);
        const float4 a1l = *(const float4*)(p1 + o);
        const float4 a1h = *(const float4*)(p1 + o + 4);
        const int4 t0 = *(const int4*)(tp + o);
        const int4 t1 = *(const int4*)(tp + o + 4);

        union { short8 s; uint4v u; } A0, A1, B0, B1;
        A0.u[0] = pk(a0l.x, a0l.y); A0.u[1] = pk(a0l.z, a0l.w);
        A0.u[2] = pk(a0h.x, a0h.y); A0.u[3] = pk(a0h.z, a0h.w);
        A1.u[0] = pk(a1l.x, a1l.y); A1.u[1] = pk(a1l.z, a1l.w);
        A1.u[2] = pk(a1h.x, a1h.y); A1.u[3] = pk(a1h.z, a1h.w);
        B0.u[0] = oh2(t0.x, t0.y, m);      B0.u[1] = oh2(t0.z, t0.w, m);
        B0.u[2] = oh2(t1.x, t1.y, m);      B0.u[3] = oh2(t1.z, t1.w, m);
        const int m16 = m + 16;
        B1.u[0] = oh2(t0.x, t0.y, m16);    B1.u[1] = oh2(t0.z, t0.w, m16);
        B1.u[2] = oh2(t1.x, t1.y, m16);    B1.u[3] = oh2(t1.z, t1.w, m16);

        acc00 = __builtin_amdgcn_mfma_f32_16x16x32_bf16(A0.s, B0.s, acc00, 0, 0, 0);
        acc01 = __builtin_amdgcn_mfma_f32_16x16x32_bf16(A0.s, B1.s, acc01, 0, 0, 0);
        acc10 = __builtin_amdgcn_mfma_f32_16x16x32_bf16(A1.s, B0.s, acc10, 0, 0, 0);
        acc11 = __builtin_amdgcn_mfma_f32_16x16x32_bf16(A1.s, B1.s, acc11, 0, 0, 0);
    }

    // cross-wave reduce in LDS, then one global atomic per entry
    __shared__ float red[4][CC][CC];   // 16 KB
    #pragma unroll
    for (int r = 0; r < 4; ++r) {      // C layout: row=quad*4+r, col=m (m89-verified)
        red[w][quad*4 + r     ][m     ] = acc00[r];
        red[w][quad*4 + r     ][m + 16] = acc01[r];
        red[w][quad*4 + r + 16][m     ] = acc10[r];
        red[w][quad*4 + r + 16][m + 16] = acc11[r];
    }
    __syncthreads();

    float* Tb = T + (long)b * CC * CC;
    const float* rp = &red[0][0][0];
    for (int j = tid; j < CC * CC; j += 256) {
        const float s = rp[j] + rp[1024 + j] + rp[2048 + j] + rp[3072 + j];
        atomicAdd(&Tb[j], s);
    }
}

__global__ __launch_bounds__(256) void jloss_cnt(
    const int* __restrict__ target,    // [B][HW]
    float*     __restrict__ cnt)       // [B][C] pre-zeroed
{
    const int tid = threadIdx.x;
    const int l   = tid & 63;
    const int blk = blockIdx.x;
    const int b   = blk / NCNT;
    const int seg = blk % NCNT;
    const int* tb = target + (long)b * HW + (long)seg * CNT_PX + tid * 4;

    int c[CC];
    #pragma unroll
    for (int k = 0; k < CC; ++k) c[k] = 0;
    #pragma unroll
    for (int it = 0; it < CNT_PX / (256 * 4); ++it) {   // 4 iters x int4
        const int4 t = *(const int4*)(tb + it * 1024);
        #pragma unroll
        for (int k = 0; k < CC; ++k)
            c[k] += (int)__popcll(__ballot(t.x == k)) + (int)__popcll(__ballot(t.y == k))
                  + (int)__popcll(__ballot(t.z == k)) + (int)__popcll(__ballot(t.w == k));
    }
    if (l == 0) {
        #pragma unroll
        for (int k = 0; k < CC; ++k)
            atomicAdd(&cnt[b * CC + k], (float)c[k]);
    }
}

__global__ __launch_bounds__(256) void jloss_final(
    const float* __restrict__ T,
    const float* __restrict__ cnt,
    float*       __restrict__ out)
{
    const int b   = blockIdx.x;
    const int tid = threadIdx.x;
    __shared__ float diag_s[CC];
    __shared__ float inv_n[CC];
    __shared__ float wsum[4];

    const float* Tb = T + (long)b * CC * CC;
    const float* cb = cnt + b * CC;

    if (tid < CC) {
        const float inv = 1.0f / cb[tid];
        inv_n[tid]  = inv;
        diag_s[tid] = Tb[tid * CC + tid] * inv;
    }
    __syncthreads();

    float sum = 0.0f;
    for (int idx = tid; idx < CC * CC; idx += 256) {
        const int i = idx >> 5;
        const int k = idx & 31;
        if (i != k) {
            const float S = Tb[idx] * inv_n[k];
            sum += logf(0.5f + 0.5f * (diag_s[i] - S));
        }
    }
    #pragma unroll
    for (int off = 32; off > 0; off >>= 1) sum += __shfl_down(sum, off, 64);
    if ((tid & 63) == 0) wsum[tid >> 6] = sum;
    __syncthreads();
    if (tid == 0) out[b] = -(wsum[0] + wsum[1] + wsum[2] + wsum[3]);
}

extern "C" void kernel_launch(void* const* d_in, const int* in_sizes, int n_in,
                              void* d_out, int out_size, void* d_ws, size_t ws_size,
                              hipStream_t stream) {
    const float* pred   = (const float*)d_in[0];
    const int*   target = (const int*)d_in[1];
    float* out = (float*)d_out;

    float* T   = (float*)d_ws;                       // 8*32*32 floats
    float* cnt = (float*)d_ws + BB * CC * CC;        // 8*32 floats

    hipMemsetAsync(d_ws, 0, (BB * CC * CC + BB * CC) * sizeof(float), stream);

    jloss_cnt  <<<BB * NCNT,   256, 0, stream>>>(target, cnt);
    jloss_mfma <<<BB * NCHUNK, 256, 0, stream>>>(pred, target, T);
    jloss_final<<<BB, 256, 0, stream>>>(T, cnt, out);
}

// Round 8
// 217.987 us; speedup vs baseline: 1.3563x; 1.3563x over previous
//
#include <hip/hip_runtime.h>

// J-loss via MFMA: T[b,i,k] = sum_p pred[b,i,p] * onehot(target[b,p]==k)
// j[b] = -sum_{i!=k} log(0.5 + 0.5*(T[b,i,i]/n[b,i] - T[b,i,k]/n[b,k]))
//
// R7 post-mortem: confounded (unroll1+chunk512+lb6+cnt kernel) -> 295us; dead end.
// R8 = EXACT R3 structure (best, 222.5us) + ONE variable: nontemporal loads
// on pred/target (nt/sc1 — skip L1/L2 retention for the 151MB once-streamed
// input). Everything else byte-identical to R3.

#define BB 8
#define CC 32
#define HW 147456                 // 384*384
#define CHUNK_PX 1024             // pixels per block (4 waves x 256 px)
#define NCHUNK (HW / CHUNK_PX)    // 144

typedef __attribute__((ext_vector_type(8))) short short8;
typedef __attribute__((ext_vector_type(4))) float float4v;
typedef __attribute__((ext_vector_type(4))) unsigned uint4v;
typedef __attribute__((ext_vector_type(4))) int int4v;

// pack trunc-bf16(lo), trunc-bf16(hi) into one dword: 1 v_perm_b32
__device__ __forceinline__ unsigned pk(float lo, float hi) {
    return __builtin_amdgcn_perm(__float_as_uint(hi), __float_as_uint(lo), 0x07060302u);
}
// packed pair of one-hot bf16 values for classes (ta,tb) vs m
__device__ __forceinline__ unsigned oh2(int ta, int tb, int m) {
    return (ta == m ? 0x3F80u : 0u) | (tb == m ? 0x3F800000u : 0u);
}

__global__ __launch_bounds__(256, 4) void jloss_mfma(
    const float* __restrict__ pred,    // [B][C][HW]
    const int*   __restrict__ target,  // [B][HW]
    float*       __restrict__ T,       // [B][C][C] pre-zeroed
    float*       __restrict__ cnt)     // [B][C]    pre-zeroed
{
    const int tid  = threadIdx.x;
    const int w    = tid >> 6;         // wave 0..3
    const int l    = tid & 63;
    const int quad = l >> 4;
    const int m    = l & 15;
    const int blk  = blockIdx.x;
    const int b    = blk / NCHUNK;
    const int chunk= blk % NCHUNK;

    const long pb_wave = (long)chunk * CHUNK_PX + w * 256;
    const float* predb = pred + (long)b * CC * HW;
    const int*   tgtb  = target + (long)b * HW;

    float4v acc00 = {0,0,0,0}, acc01 = {0,0,0,0};
    float4v acc10 = {0,0,0,0}, acc11 = {0,0,0,0};
    float4v accc0 = {0,0,0,0}, accc1 = {0,0,0,0};   // counts: ones . B
    const short8 ONES = {0x3F80,0x3F80,0x3F80,0x3F80,0x3F80,0x3F80,0x3F80,0x3F80};

    #pragma unroll 2
    for (int ks = 0; ks < 8; ++ks) {   // 8 K-steps of 32 pixels
        const long po = pb_wave + ks * 32 + quad * 8;
        const float* p0 = predb + (long)m * HW + po;   // channel m
        const float* p1 = p0 + (long)16 * HW;          // channel m+16
        const float4v a0l = __builtin_nontemporal_load((const float4v*)p0);
        const float4v a0h = __builtin_nontemporal_load((const float4v*)(p0 + 4));
        const float4v a1l = __builtin_nontemporal_load((const float4v*)p1);
        const float4v a1h = __builtin_nontemporal_load((const float4v*)(p1 + 4));
        const int4v t0 = __builtin_nontemporal_load((const int4v*)(tgtb + po));
        const int4v t1 = __builtin_nontemporal_load((const int4v*)(tgtb + po + 4));

        union { short8 s; uint4v u; } A0, A1, B0, B1;
        A0.u[0] = pk(a0l[0], a0l[1]); A0.u[1] = pk(a0l[2], a0l[3]);
        A0.u[2] = pk(a0h[0], a0h[1]); A0.u[3] = pk(a0h[2], a0h[3]);
        A1.u[0] = pk(a1l[0], a1l[1]); A1.u[1] = pk(a1l[2], a1l[3]);
        A1.u[2] = pk(a1h[0], a1h[1]); A1.u[3] = pk(a1h[2], a1h[3]);
        B0.u[0] = oh2(t0[0], t0[1], m);      B0.u[1] = oh2(t0[2], t0[3], m);
        B0.u[2] = oh2(t1[0], t1[1], m);      B0.u[3] = oh2(t1[2], t1[3], m);
        const int m16 = m + 16;
        B1.u[0] = oh2(t0[0], t0[1], m16);    B1.u[1] = oh2(t0[2], t0[3], m16);
        B1.u[2] = oh2(t1[0], t1[1], m16);    B1.u[3] = oh2(t1[2], t1[3], m16);

        acc00 = __builtin_amdgcn_mfma_f32_16x16x32_bf16(A0.s, B0.s, acc00, 0, 0, 0);
        acc01 = __builtin_amdgcn_mfma_f32_16x16x32_bf16(A0.s, B1.s, acc01, 0, 0, 0);
        acc10 = __builtin_amdgcn_mfma_f32_16x16x32_bf16(A1.s, B0.s, acc10, 0, 0, 0);
        acc11 = __builtin_amdgcn_mfma_f32_16x16x32_bf16(A1.s, B1.s, acc11, 0, 0, 0);
        accc0 = __builtin_amdgcn_mfma_f32_16x16x32_bf16(ONES, B0.s, accc0, 0, 0, 0);
        accc1 = __builtin_amdgcn_mfma_f32_16x16x32_bf16(ONES, B1.s, accc1, 0, 0, 0);
    }

    // cross-wave reduce in LDS, then one global atomic per entry
    __shared__ float red[4][CC][CC];   // 16 KB
    __shared__ float redc[4][CC];
    #pragma unroll
    for (int r = 0; r < 4; ++r) {      // C layout: row=quad*4+r, col=m (m89-verified)
        red[w][quad*4 + r     ][m     ] = acc00[r];
        red[w][quad*4 + r     ][m + 16] = acc01[r];
        red[w][quad*4 + r + 16][m     ] = acc10[r];
        red[w][quad*4 + r + 16][m + 16] = acc11[r];
    }
    if (quad == 0) {                   // counts: every row of accc is count[col]
        redc[w][m]      = accc0[0];
        redc[w][m + 16] = accc1[0];
    }
    __syncthreads();

    float* Tb = T + (long)b * CC * CC;
    const float* rp = &red[0][0][0];
    for (int j = tid; j < CC * CC; j += 256) {
        const float s = rp[j] + rp[1024 + j] + rp[2048 + j] + rp[3072 + j];
        atomicAdd(&Tb[j], s);
    }
    if (tid < CC)
        atomicAdd(&cnt[b * CC + tid],
                  redc[0][tid] + redc[1][tid] + redc[2][tid] + redc[3][tid]);
}

__global__ __launch_bounds__(256) void jloss_final(
    const float* __restrict__ T,
    const float* __restrict__ cnt,
    float*       __restrict__ out)
{
    const int b   = blockIdx.x;
    const int tid = threadIdx.x;
    __shared__ float diag_s[CC];
    __shared__ float inv_n[CC];
    __shared__ float wsum[4];

    const float* Tb = T + (long)b * CC * CC;
    const float* cb = cnt + b * CC;

    if (tid < CC) {
        const float inv = 1.0f / cb[tid];
        inv_n[tid]  = inv;
        diag_s[tid] = Tb[tid * CC + tid] * inv;
    }
    __syncthreads();

    float sum = 0.0f;
    for (int idx = tid; idx < CC * CC; idx += 256) {
        const int i = idx >> 5;
        const int k = idx & 31;
        if (i != k) {
            const float S = Tb[idx] * inv_n[k];
            sum += logf(0.5f + 0.5f * (diag_s[i] - S));
        }
    }
    #pragma unroll
    for (int off = 32; off > 0; off >>= 1) sum += __shfl_down(sum, off, 64);
    if ((tid & 63) == 0) wsum[tid >> 6] = sum;
    __syncthreads();
    if (tid == 0) out[b] = -(wsum[0] + wsum[1] + wsum[2] + wsum[3]);
}

extern "C" void kernel_launch(void* const* d_in, const int* in_sizes, int n_in,
                              void* d_out, int out_size, void* d_ws, size_t ws_size,
                              hipStream_t stream) {
    const float* pred   = (const float*)d_in[0];
    const int*   target = (const int*)d_in[1];
    float* out = (float*)d_out;

    float* T   = (float*)d_ws;                       // 8*32*32 floats
    float* cnt = (float*)d_ws + BB * CC * CC;        // 8*32 floats

    hipMemsetAsync(d_ws, 0, (BB * CC * CC + BB * CC) * sizeof(float), stream);

    jloss_mfma <<<BB * NCHUNK, 256, 0, stream>>>(pred, target, T, cnt);
    jloss_final<<<BB, 256, 0, stream>>>(T, cnt, out);
}